// Round 6
// baseline (1180.989 us; speedup 1.0000x reference)
//
#include <hip/hip_runtime.h>
#include <hip/hip_fp16.h>

#define TT   2048
#define BB   64
#define II   16
#define HH   8
#define HIDN 64
#define GG   256   // 4*HIDN
#define T4   (TT / 4)

typedef _Float16 h2  __attribute__((ext_vector_type(2)));
typedef _Float16 h4  __attribute__((ext_vector_type(4)));
typedef _Float16 h8  __attribute__((ext_vector_type(8)));
typedef _Float16 h16 __attribute__((ext_vector_type(16)));
typedef _Float16 h64 __attribute__((ext_vector_type(64)));

__device__ __forceinline__ float fdot2(h2 a, h2 b, float c) {
    return __builtin_amdgcn_fdot2(a, b, c, false);
}
__device__ __forceinline__ float fast_sigmoid(float z) {
    return __builtin_amdgcn_rcpf(1.0f + __expf(-z));
}
__device__ __forceinline__ float fast_tanh(float z) {
    return fmaf(2.0f, __builtin_amdgcn_rcpf(1.0f + __expf(-2.0f * z)), -1.0f);
}

// constant-index 2-element slice of a wider f16 vector: free subregister view
#define SL2(v, j) __builtin_shufflevector(v, v, 2 * (j), 2 * (j) + 1)

// ---------------- x -> f16 conversion (one-time, trivial) ----------------
__global__ void cvt_x_kernel(const float* __restrict__ x, _Float16* __restrict__ xh, int n4) {
    int i = blockIdx.x * blockDim.x + threadIdx.x;
    if (i < n4) {
        float4 v = ((const float4*)x)[i];
        ((h2*)xh)[2 * i]     = h2{ (_Float16)v.x, (_Float16)v.y };
        ((h2*)xh)[2 * i + 1] = h2{ (_Float16)v.z, (_Float16)v.w };
    }
}

// ---------------- main recurrent kernel: ONE WAVE PER CHAIN ----------------
// R5 post-mortem: the weight C-arrays were never SROA-promoted (dynamic indices
// at SROA time; unroll happens later) -> they lived in SCRATCH and every step
// re-loaded ~160 values via scratch_load (the ~800 stall cyc/step; VGPR stuck
// at ~136 with VALUBusy matching only the real dot work). Fix: NO allocas in
// the hot loop. Weights are SSA ext-vector values (h64 per gate for W_hh, h16
// per gate for W_ih), sliced with compile-time shufflevector; LDS h-read is 8
// named h8 values; x buffer is one h16; stage pack is one h4.
template <int STAGE, bool XF16>   // STAGE 1: slab f16; STAGE 2: atomic fallback
__global__ __launch_bounds__(64, 1)
void lstm_wave(const float* __restrict__ x,
               const _Float16* __restrict__ xh,
               const float* __restrict__ Wih,
               const float* __restrict__ Whh,
               const float* __restrict__ bih,
               const float* __restrict__ bhh,
               const float* __restrict__ Wlin,
               const float* __restrict__ blin,
               float* __restrict__ out,        // (T,B,H)      (STAGE==2 only)
               float* __restrict__ lstm_out,   // (T,B,HIDN)   (STAGE==2 atomics)
               _Float16* __restrict__ stage_f16)  // [T/4][512][64][4]
{
    const int lane = threadIdx.x;          // hidden unit index
    const int c    = blockIdx.x;           // chain id
    const int b    = c & (BB - 1);
    const int hd   = c >> 6;

    // ---- per-lane weights as SSA vector values (no allocas) ----
    h64 w0, w1, w2, w3;       // W_hh rows, gates i,f,g,o   (32 VGPRs each)
    h16 u0, u1, u2, u3;       // W_ih rows                  (8 VGPRs each)
    float b0, b1, b2, b3;

#define INITG(W, U, Bv, g)                                                     \
    {                                                                          \
        const int r = hd * GG + (g) * HIDN + lane;                             \
        const float4* p = (const float4*)(Whh + (size_t)r * HIDN);             \
        _Pragma("unroll") for (int q = 0; q < 16; ++q) {                       \
            float4 v = p[q];                                                   \
            W[4 * q + 0] = (_Float16)v.x; W[4 * q + 1] = (_Float16)v.y;        \
            W[4 * q + 2] = (_Float16)v.z; W[4 * q + 3] = (_Float16)v.w;        \
        }                                                                      \
        const float4* pi = (const float4*)(Wih + (size_t)r * II);              \
        _Pragma("unroll") for (int q = 0; q < 4; ++q) {                        \
            float4 v = pi[q];                                                  \
            U[4 * q + 0] = (_Float16)v.x; U[4 * q + 1] = (_Float16)v.y;        \
            U[4 * q + 2] = (_Float16)v.z; U[4 * q + 3] = (_Float16)v.w;        \
        }                                                                      \
        Bv = bih[r] + bhh[r];                                                  \
    }
    INITG(w0, u0, b0, 0)
    INITG(w1, u1, b1, 1)
    INITG(w2, u2, b2, 2)
    INITG(w3, u3, b3, 3)
#undef INITG

    float wl = 0.0f, bl = 0.0f;
    if (STAGE == 2) { wl = Wlin[hd * HIDN + lane]; bl = blin[hd]; }

    __shared__ __align__(16) _Float16 hbuf[HIDN];  // 128 B, wave-synchronous
    hbuf[lane] = (_Float16)0.0f;   // in-order LDS pipe: visible to reads below

    float cst = 0.0f;

    const _Float16* xhp = xh + b * II;
    const float*    xfp = x + b * II;

    auto load_x = [&](int t) -> h16 {
        int tc = t < TT ? t : TT - 1;   // branchless clamp (avoid OOB)
        if (XF16) {
            const h8* p = (const h8*)(xhp + (size_t)tc * BB * II);
            h8 a = p[0], bb2 = p[1];
            return __builtin_shufflevector(a, bb2, 0, 1, 2, 3, 4, 5, 6, 7,
                                           8, 9, 10, 11, 12, 13, 14, 15);
        } else {
            const float4* p = (const float4*)(xfp + (size_t)tc * BB * II);
            h16 d;
#pragma unroll
            for (int q = 0; q < 4; ++q) {
                float4 v = p[q];
                d[4 * q + 0] = (_Float16)v.x; d[4 * q + 1] = (_Float16)v.y;
                d[4 * q + 2] = (_Float16)v.z; d[4 * q + 3] = (_Float16)v.w;
            }
            return d;
        }
    };
    h16 xv = load_x(0);

    // stage pointer: f16 index = t4*131072 + c*256 + lane*4 ; bump 131072/t4
    h4* sptr = (h4*)(stage_f16 + (size_t)c * 256 + lane * 4);

    const h8* hb = (const h8*)hbuf;

    for (int t4 = 0; t4 < T4; ++t4) {
        h4 hpv;
#pragma unroll
        for (int j = 0; j < 4; ++j) {
            const int t = t4 * 4 + j;
            h16 xn = load_x(t + 1);

            // h broadcast: 8 named h8 SSA values (8 x ds_read_b128)
            h8 r0 = hb[0], r1 = hb[1], r2 = hb[2], r3 = hb[3];
            h8 r4 = hb[4], r5 = hb[5], r6 = hb[6], r7 = hb[7];

            float z0 = b0, z1 = b1, z2 = b2, z3 = b3;

            // x-dots first: real work under the ds_read latency
#define DOTX1(i)                                   \
            z0 = fdot2(SL2(u0, i), SL2(xv, i), z0); \
            z1 = fdot2(SL2(u1, i), SL2(xv, i), z1); \
            z2 = fdot2(SL2(u2, i), SL2(xv, i), z2); \
            z3 = fdot2(SL2(u3, i), SL2(xv, i), z3);
            DOTX1(0) DOTX1(1) DOTX1(2) DOTX1(3)
            DOTX1(4) DOTX1(5) DOTX1(6) DOTX1(7)
#undef DOTX1

#define DOTH1(i, rm, jj)                                 \
            z0 = fdot2(SL2(w0, i), SL2(rm, jj), z0);     \
            z1 = fdot2(SL2(w1, i), SL2(rm, jj), z1);     \
            z2 = fdot2(SL2(w2, i), SL2(rm, jj), z2);     \
            z3 = fdot2(SL2(w3, i), SL2(rm, jj), z3);
#define DOTH4(rm, base)                                  \
            DOTH1((base) + 0, rm, 0) DOTH1((base) + 1, rm, 1) \
            DOTH1((base) + 2, rm, 2) DOTH1((base) + 3, rm, 3)
            DOTH4(r0, 0)  DOTH4(r1, 4)  DOTH4(r2, 8)  DOTH4(r3, 12)
            DOTH4(r4, 16) DOTH4(r5, 20) DOTH4(r6, 24) DOTH4(r7, 28)
#undef DOTH4
#undef DOTH1

            float gi = fast_sigmoid(z0);
            float gf = fast_sigmoid(z1);
            float gg = fast_tanh(z2);
            float go = fast_sigmoid(z3);

            cst = fmaf(gf, cst, gi * gg);
            float h = go * fast_tanh(cst);
            _Float16 h16s = (_Float16)h;

            hbuf[lane] = h16s;           // in-order after this step's reads
            hpv[j] = h16s;               // SSA vector insert (folded post-unroll)

            if (STAGE == 2) {
                atomicAdd(&lstm_out[((size_t)t * BB + b) * HIDN + lane], h);
                float p = h * wl;
                p += __shfl_down(p, 32, 64);
                p += __shfl_down(p, 16, 64);
                p += __shfl_down(p, 8, 64);
                p += __shfl_down(p, 4, 64);
                p += __shfl_down(p, 2, 64);
                p += __shfl_down(p, 1, 64);
                if (lane == 0) out[((size_t)t * BB + b) * HH + hd] = p + bl;
            }

            xv = xn;
        }
        if (STAGE == 1) {
            *sptr = hpv;                 // 8B fire-and-forget, acks amortized x4
            sptr += 512 * 64;            // 131072 f16 / 4 per h4
        }
    }
}

// ---------------- pass 2a: lstm_out[t,b,k] = sum_hd h ----------------
// block = (b, 64-t tile); 256 threads = (k, q). Coalesced reads & writes.
__global__ __launch_bounds__(256)
void pass_lstm(const _Float16* __restrict__ stage, float* __restrict__ lstm_out)
{
    const int tid  = threadIdx.x;
    const int k    = tid & (HIDN - 1);
    const int q    = tid >> 6;                 // 0..3
    const int b    = blockIdx.x & (BB - 1);
    const int tile = blockIdx.x >> 6;          // 0..31
    const h4* sp = (const h4*)stage;

#pragma unroll
    for (int g = 0; g < 4; ++g) {
        const int t4 = tile * 16 + q + 4 * g;
        float acc0 = 0.f, acc1 = 0.f, acc2 = 0.f, acc3 = 0.f;
#pragma unroll
        for (int hd = 0; hd < HH; ++hd) {
            h4 v = sp[((size_t)t4 * 512 + hd * 64 + b) * 64 + k];
            acc0 += (float)v.x; acc1 += (float)v.y;
            acc2 += (float)v.z; acc3 += (float)v.w;
        }
        const size_t t = (size_t)t4 * 4;
        lstm_out[((t + 0) * BB + b) * HIDN + k] = acc0;
        lstm_out[((t + 1) * BB + b) * HIDN + k] = acc1;
        lstm_out[((t + 2) * BB + b) * HIDN + k] = acc2;
        lstm_out[((t + 3) * BB + b) * HIDN + k] = acc3;
    }
}

// ---------------- pass 2b: out[t,b,hd] = dot(h, W_lin)+b_lin ----------------
// block = t4 (512 blocks), 512 threads = (b, hd) -> perfectly coalesced writes.
// Reads stride 512B/lane but k-loop reuses each 128B line 16x in L1.
__global__ __launch_bounds__(512)
void pass_out(const _Float16* __restrict__ stage,
              const float* __restrict__ Wlin,
              const float* __restrict__ blin,
              float* __restrict__ out)
{
    __shared__ float wls[GG * 2];   // 512 floats
    const int tid = threadIdx.x;
    wls[tid] = Wlin[tid];           // W_lin flat (8*64)
    __syncthreads();

    const int b  = tid >> 3;
    const int hd = tid & 7;
    const int c  = hd * 64 + b;
    const int t4 = blockIdx.x;
    const float bl = blin[hd];

    const h4* sp = (const h4*)stage + ((size_t)t4 * 512 + c) * 64;
    float a0 = 0.f, a1 = 0.f, a2 = 0.f, a3 = 0.f;
#pragma unroll 8
    for (int k = 0; k < HIDN; ++k) {
        h4 v = sp[k];
        float w = wls[hd * HIDN + k];
        a0 = fmaf((float)v.x, w, a0);
        a1 = fmaf((float)v.y, w, a1);
        a2 = fmaf((float)v.z, w, a2);
        a3 = fmaf((float)v.w, w, a3);
    }
    const size_t t = (size_t)t4 * 4;
    out[(t + 0) * 512 + tid] = a0 + bl;
    out[(t + 1) * 512 + tid] = a1 + bl;
    out[(t + 2) * 512 + tid] = a2 + bl;
    out[(t + 3) * 512 + tid] = a3 + bl;
}

extern "C" void kernel_launch(void* const* d_in, const int* in_sizes, int n_in,
                              void* d_out, int out_size, void* d_ws, size_t ws_size,
                              hipStream_t stream)
{
    const float* x    = (const float*)d_in[0];
    const float* Wih  = (const float*)d_in[1];
    const float* Whh  = (const float*)d_in[2];
    const float* bih  = (const float*)d_in[3];
    const float* bhh  = (const float*)d_in[4];
    const float* Wlin = (const float*)d_in[5];
    const float* blin = (const float*)d_in[6];

    float* out  = (float*)d_out;
    float* lstm = out + (size_t)TT * BB * HH;

    const size_t xbytes = (size_t)TT * BB * II * 2 + 4096;   // 4 MB + clamp slack
    const size_t slab16 = (size_t)TT * BB * HH * HIDN * 2;   // 134 MB

    const bool xf16 = ws_size >= xbytes;
    _Float16* xh = (_Float16*)d_ws;
    char* slabp  = (char*)d_ws + (xf16 ? xbytes : 0);
    size_t avail = ws_size - (xf16 ? xbytes : 0);
    const int mode = (avail >= slab16) ? 1 : 2;

    if (xf16) {
        int n4 = TT * BB * II / 4;
        cvt_x_kernel<<<(n4 + 255) / 256, 256, 0, stream>>>(x, xh, n4);
    }
    if (mode == 2) {
        hipMemsetAsync(lstm, 0, (size_t)TT * BB * HIDN * 4, stream);
    }

    dim3 grid(BB * HH), block(64);
    _Float16* sh = (_Float16*)slabp;

#define LAUNCH_MAIN(M, XF) \
    lstm_wave<M, XF><<<grid, block, 0, stream>>>(x, xh, Wih, Whh, bih, bhh, Wlin, blin, out, lstm, sh)

    if (xf16) { if (mode == 1) LAUNCH_MAIN(1, true);  else LAUNCH_MAIN(2, true); }
    else      { if (mode == 1) LAUNCH_MAIN(1, false); else LAUNCH_MAIN(2, false); }
#undef LAUNCH_MAIN

    if (mode == 1) {
        pass_lstm<<<dim3(BB * 32), dim3(256), 0, stream>>>(sh, lstm);
        pass_out <<<dim3(T4), dim3(512), 0, stream>>>(sh, Wlin, blin, out);
    }
}

// Round 8
// 1151.201 us; speedup vs baseline: 1.0259x; 1.0259x over previous
//
#include <hip/hip_runtime.h>
#include <hip/hip_fp16.h>

#define TT   2048
#define BB   64
#define II   16
#define HH   8
#define HIDN 64
#define GG   256   // 4*HIDN
#define T4   (TT / 4)

typedef _Float16 h2  __attribute__((ext_vector_type(2)));
typedef _Float16 h4  __attribute__((ext_vector_type(4)));
typedef _Float16 h8  __attribute__((ext_vector_type(8)));
typedef _Float16 h16 __attribute__((ext_vector_type(16)));
typedef _Float16 h64 __attribute__((ext_vector_type(64)));
typedef int      i32x8  __attribute__((ext_vector_type(8)));
typedef int      i32x32 __attribute__((ext_vector_type(32)));

__device__ __forceinline__ float fdot2(h2 a, h2 b, float c) {
    return __builtin_amdgcn_fdot2(a, b, c, false);
}
__device__ __forceinline__ float fast_sigmoid(float z) {
    return __builtin_amdgcn_rcpf(1.0f + __expf(-z));
}
__device__ __forceinline__ float fast_tanh(float z) {
    return fmaf(2.0f, __builtin_amdgcn_rcpf(1.0f + __expf(-2.0f * z)), -1.0f);
}

// ---- opaque register pin: value becomes the result of a non-rematerializable
// asm identity, so the scheduler CANNOT sink its producing loads/cvts into the
// loop (R6 post-mortem: legal remat of weight loads+cvts was the 2x overhead).
__device__ __forceinline__ h64 pin64(h64 v) {
    i32x32 iv = __builtin_bit_cast(i32x32, v);
#pragma unroll
    for (int i = 0; i < 32; ++i) { int t = iv[i]; asm volatile("" : "+v"(t)); iv[i] = t; }
    return __builtin_bit_cast(h64, iv);
}
__device__ __forceinline__ h16 pin16(h16 v) {
    i32x8 iv = __builtin_bit_cast(i32x8, v);
#pragma unroll
    for (int i = 0; i < 8; ++i) { int t = iv[i]; asm volatile("" : "+v"(t)); iv[i] = t; }
    return __builtin_bit_cast(h16, iv);
}
__device__ __forceinline__ float pinf(float v) {
    asm volatile("" : "+v"(v));
    return v;
}

// constant-index 2-element slice of a wider f16 vector: free subregister view
// (indices MUST be literal constants at parse time)
#define SL2(v, j) __builtin_shufflevector(v, v, 2 * (j), 2 * (j) + 1)

// ---------------- x -> f16 conversion (one-time, trivial) ----------------
__global__ void cvt_x_kernel(const float* __restrict__ x, _Float16* __restrict__ xh, int n4) {
    int i = blockIdx.x * blockDim.x + threadIdx.x;
    if (i < n4) {
        float4 v = ((const float4*)x)[i];
        ((h2*)xh)[2 * i]     = h2{ (_Float16)v.x, (_Float16)v.y };
        ((h2*)xh)[2 * i + 1] = h2{ (_Float16)v.z, (_Float16)v.w };
    }
}

// ---------------- main recurrent kernel: ONE WAVE PER CHAIN ----------------
// lane = hidden unit; all 4 gate rows of the unit computed in-lane; h exchanged
// via a 128B wave-synchronous LDS buffer (zero barriers). Weights are PINNED
// into VGPRs (see pin64). The x-projection zx(t+1)=bias+W_ih.x(t+1) is computed
// at the END of step t (x prefetched), so each step opens ds_read -> h-dots.
template <int STAGE, bool XF16>   // STAGE 1: slab f16; STAGE 2: atomic fallback
__global__ __launch_bounds__(64, 1)
void lstm_wave(const float* __restrict__ x,
               const _Float16* __restrict__ xh,
               const float* __restrict__ Wih,
               const float* __restrict__ Whh,
               const float* __restrict__ bih,
               const float* __restrict__ bhh,
               const float* __restrict__ Wlin,
               const float* __restrict__ blin,
               float* __restrict__ out,        // (T,B,H)      (STAGE==2 only)
               float* __restrict__ lstm_out,   // (T,B,HIDN)   (STAGE==2 atomics)
               _Float16* __restrict__ stage_f16)  // [T/4][512][64][4]
{
    const int lane = threadIdx.x;          // hidden unit index
    const int c    = blockIdx.x;           // chain id
    const int b    = c & (BB - 1);
    const int hd   = c >> 6;

    // ---- per-lane weights as SSA vector values, then PINNED ----
    h64 w0, w1, w2, w3;       // W_hh rows, gates i,f,g,o   (32 VGPRs each)
    h16 u0, u1, u2, u3;       // W_ih rows                  (8 VGPRs each)
    float b0, b1, b2, b3;

#define INITG(W, U, Bv, g)                                                     \
    {                                                                          \
        const int r = hd * GG + (g) * HIDN + lane;                             \
        const float4* p = (const float4*)(Whh + (size_t)r * HIDN);             \
        _Pragma("unroll") for (int q = 0; q < 16; ++q) {                       \
            float4 v = p[q];                                                   \
            W[4 * q + 0] = (_Float16)v.x; W[4 * q + 1] = (_Float16)v.y;        \
            W[4 * q + 2] = (_Float16)v.z; W[4 * q + 3] = (_Float16)v.w;        \
        }                                                                      \
        const float4* pi = (const float4*)(Wih + (size_t)r * II);              \
        _Pragma("unroll") for (int q = 0; q < 4; ++q) {                        \
            float4 v = pi[q];                                                  \
            U[4 * q + 0] = (_Float16)v.x; U[4 * q + 1] = (_Float16)v.y;        \
            U[4 * q + 2] = (_Float16)v.z; U[4 * q + 3] = (_Float16)v.w;        \
        }                                                                      \
        Bv = bih[r] + bhh[r];                                                  \
    }
    INITG(w0, u0, b0, 0)
    INITG(w1, u1, b1, 1)
    INITG(w2, u2, b2, 2)
    INITG(w3, u3, b3, 3)
#undef INITG

    w0 = pin64(w0); w1 = pin64(w1); w2 = pin64(w2); w3 = pin64(w3);
    u0 = pin16(u0); u1 = pin16(u1); u2 = pin16(u2); u3 = pin16(u3);
    b0 = pinf(b0);  b1 = pinf(b1);  b2 = pinf(b2);  b3 = pinf(b3);

    float wl = 0.0f, bl = 0.0f;
    if (STAGE == 2) { wl = Wlin[hd * HIDN + lane]; bl = blin[hd]; }

    __shared__ __align__(16) _Float16 hbuf[HIDN];  // 128 B, wave-synchronous
    hbuf[lane] = (_Float16)0.0f;   // in-order LDS pipe: visible to reads below

    float cst = 0.0f;

    const _Float16* xhp = xh + b * II;
    const float*    xfp = x + b * II;

    auto load_x = [&](int t) -> h16 {
        int tc = t < TT ? t : TT - 1;   // branchless clamp (avoid OOB)
        if (XF16) {
            const h8* p = (const h8*)(xhp + (size_t)tc * BB * II);
            h8 a = p[0], bb2 = p[1];
            return __builtin_shufflevector(a, bb2, 0, 1, 2, 3, 4, 5, 6, 7,
                                           8, 9, 10, 11, 12, 13, 14, 15);
        } else {
            const float4* p = (const float4*)(xfp + (size_t)tc * BB * II);
            h16 d;
#pragma unroll
            for (int q = 0; q < 4; ++q) {
                float4 v = p[q];
                d[4 * q + 0] = (_Float16)v.x; d[4 * q + 1] = (_Float16)v.y;
                d[4 * q + 2] = (_Float16)v.z; d[4 * q + 3] = (_Float16)v.w;
            }
            return d;
        }
    };

    // literal-index x-dot sequence (shufflevector needs parse-time constants)
#define DOTX1(xr, i)                                \
    zx0 = fdot2(SL2(u0, i), SL2(xr, i), zx0);       \
    zx1 = fdot2(SL2(u1, i), SL2(xr, i), zx1);       \
    zx2 = fdot2(SL2(u2, i), SL2(xr, i), zx2);       \
    zx3 = fdot2(SL2(u3, i), SL2(xr, i), zx3);
#define DOTX(xr)                                    \
    DOTX1(xr, 0) DOTX1(xr, 1) DOTX1(xr, 2) DOTX1(xr, 3) \
    DOTX1(xr, 4) DOTX1(xr, 5) DOTX1(xr, 6) DOTX1(xr, 7)

    // zx for step 0
    float zx0 = b0, zx1 = b1, zx2 = b2, zx3 = b3;
    {
        h16 x0 = load_x(0);
        DOTX(x0)
    }

    // stage pointer: f16 index = t4*131072 + c*256 + lane*4 ; bump 131072/t4
    h4* sptr = (h4*)(stage_f16 + (size_t)c * 256 + lane * 4);

    const h8* hb = (const h8*)hbuf;

    for (int t4 = 0; t4 < T4; ++t4) {
        h4 hpv;
#pragma unroll
        for (int j = 0; j < 4; ++j) {
            const int t = t4 * 4 + j;
            h16 xn = load_x(t + 1);   // issue early; consumed at step end

            // h broadcast: 8 named h8 SSA values (8 x ds_read_b128)
            h8 r0 = hb[0], r1 = hb[1], r2 = hb[2], r3 = hb[3];
            h8 r4 = hb[4], r5 = hb[5], r6 = hb[6], r7 = hb[7];

            // z = zx (carried; includes bias + W_ih.x) + W_hh.h
            float z0 = zx0, z1 = zx1, z2 = zx2, z3 = zx3;

#define DOTH1(i, rm, jj)                                 \
            z0 = fdot2(SL2(w0, i), SL2(rm, jj), z0);     \
            z1 = fdot2(SL2(w1, i), SL2(rm, jj), z1);     \
            z2 = fdot2(SL2(w2, i), SL2(rm, jj), z2);     \
            z3 = fdot2(SL2(w3, i), SL2(rm, jj), z3);
#define DOTH4(rm, base)                                  \
            DOTH1((base) + 0, rm, 0) DOTH1((base) + 1, rm, 1) \
            DOTH1((base) + 2, rm, 2) DOTH1((base) + 3, rm, 3)
            DOTH4(r0, 0)  DOTH4(r1, 4)  DOTH4(r2, 8)  DOTH4(r3, 12)
            DOTH4(r4, 16) DOTH4(r5, 20) DOTH4(r6, 24) DOTH4(r7, 28)
#undef DOTH4
#undef DOTH1

            float gi = fast_sigmoid(z0);
            float gf = fast_sigmoid(z1);
            float gg = fast_tanh(z2);
            float go = fast_sigmoid(z3);

            cst = fmaf(gf, cst, gi * gg);
            float h = go * fast_tanh(cst);
            _Float16 h16s = (_Float16)h;

            hbuf[lane] = h16s;           // in-order after this step's reads
            hpv[j] = h16s;               // SSA vector insert

            // x-projection for step t+1 (off the recurrence critical path)
            zx0 = b0; zx1 = b1; zx2 = b2; zx3 = b3;
            DOTX(xn)

            if (STAGE == 2) {
                atomicAdd(&lstm_out[((size_t)t * BB + b) * HIDN + lane], h);
                float p = h * wl;
                p += __shfl_down(p, 32, 64);
                p += __shfl_down(p, 16, 64);
                p += __shfl_down(p, 8, 64);
                p += __shfl_down(p, 4, 64);
                p += __shfl_down(p, 2, 64);
                p += __shfl_down(p, 1, 64);
                if (lane == 0) out[((size_t)t * BB + b) * HH + hd] = p + bl;
            }
        }
        if (STAGE == 1) {
            *sptr = hpv;                 // 8B fire-and-forget, acks amortized x4
            sptr += 512 * 64;            // 131072 f16 / 4 per h4
        }
    }
#undef DOTX
#undef DOTX1
}

// ---------------- pass 2a: lstm_out[t,b,k] = sum_hd h ----------------
// block = (b, 64-t tile); 256 threads = (k, q). Coalesced reads & writes.
__global__ __launch_bounds__(256)
void pass_lstm(const _Float16* __restrict__ stage, float* __restrict__ lstm_out)
{
    const int tid  = threadIdx.x;
    const int k    = tid & (HIDN - 1);
    const int q    = tid >> 6;                 // 0..3
    const int b    = blockIdx.x & (BB - 1);
    const int tile = blockIdx.x >> 6;          // 0..31
    const h4* sp = (const h4*)stage;

#pragma unroll
    for (int g = 0; g < 4; ++g) {
        const int t4 = tile * 16 + q + 4 * g;
        float acc0 = 0.f, acc1 = 0.f, acc2 = 0.f, acc3 = 0.f;
#pragma unroll
        for (int hd = 0; hd < HH; ++hd) {
            h4 v = sp[((size_t)t4 * 512 + hd * 64 + b) * 64 + k];
            acc0 += (float)v.x; acc1 += (float)v.y;
            acc2 += (float)v.z; acc3 += (float)v.w;
        }
        const size_t t = (size_t)t4 * 4;
        lstm_out[((t + 0) * BB + b) * HIDN + k] = acc0;
        lstm_out[((t + 1) * BB + b) * HIDN + k] = acc1;
        lstm_out[((t + 2) * BB + b) * HIDN + k] = acc2;
        lstm_out[((t + 3) * BB + b) * HIDN + k] = acc3;
    }
}

// ---------------- pass 2b: out[t,b,hd] = dot(h, W_lin)+b_lin ----------------
// block = t4 (512 blocks), 512 threads = (b, hd) -> perfectly coalesced writes.
// Reads stride 512B/lane but k-loop reuses each 128B line 16x in L1.
__global__ __launch_bounds__(512)
void pass_out(const _Float16* __restrict__ stage,
              const float* __restrict__ Wlin,
              const float* __restrict__ blin,
              float* __restrict__ out)
{
    __shared__ float wls[GG * 2];   // 512 floats
    const int tid = threadIdx.x;
    wls[tid] = Wlin[tid];           // W_lin flat (8*64)
    __syncthreads();

    const int b  = tid >> 3;
    const int hd = tid & 7;
    const int c  = hd * 64 + b;
    const int t4 = blockIdx.x;
    const float bl = blin[hd];

    const h4* sp = (const h4*)stage + ((size_t)t4 * 512 + c) * 64;
    float a0 = 0.f, a1 = 0.f, a2 = 0.f, a3 = 0.f;
#pragma unroll 8
    for (int k = 0; k < HIDN; ++k) {
        h4 v = sp[k];
        float w = wls[hd * HIDN + k];
        a0 = fmaf((float)v.x, w, a0);
        a1 = fmaf((float)v.y, w, a1);
        a2 = fmaf((float)v.z, w, a2);
        a3 = fmaf((float)v.w, w, a3);
    }
    const size_t t = (size_t)t4 * 4;
    out[(t + 0) * 512 + tid] = a0 + bl;
    out[(t + 1) * 512 + tid] = a1 + bl;
    out[(t + 2) * 512 + tid] = a2 + bl;
    out[(t + 3) * 512 + tid] = a3 + bl;
}

extern "C" void kernel_launch(void* const* d_in, const int* in_sizes, int n_in,
                              void* d_out, int out_size, void* d_ws, size_t ws_size,
                              hipStream_t stream)
{
    const float* x    = (const float*)d_in[0];
    const float* Wih  = (const float*)d_in[1];
    const float* Whh  = (const float*)d_in[2];
    const float* bih  = (const float*)d_in[3];
    const float* bhh  = (const float*)d_in[4];
    const float* Wlin = (const float*)d_in[5];
    const float* blin = (const float*)d_in[6];

    float* out  = (float*)d_out;
    float* lstm = out + (size_t)TT * BB * HH;

    const size_t xbytes = (size_t)TT * BB * II * 2 + 4096;   // 4 MB + clamp slack
    const size_t slab16 = (size_t)TT * BB * HH * HIDN * 2;   // 134 MB

    const bool xf16 = ws_size >= xbytes;
    _Float16* xh = (_Float16*)d_ws;
    char* slabp  = (char*)d_ws + (xf16 ? xbytes : 0);
    size_t avail = ws_size - (xf16 ? xbytes : 0);
    const int mode = (avail >= slab16) ? 1 : 2;

    if (xf16) {
        int n4 = TT * BB * II / 4;
        cvt_x_kernel<<<(n4 + 255) / 256, 256, 0, stream>>>(x, xh, n4);
    }
    if (mode == 2) {
        (void)hipMemsetAsync(lstm, 0, (size_t)TT * BB * HIDN * 4, stream);
    }

    dim3 grid(BB * HH), block(64);
    _Float16* sh = (_Float16*)slabp;

#define LAUNCH_MAIN(M, XF) \
    lstm_wave<M, XF><<<grid, block, 0, stream>>>(x, xh, Wih, Whh, bih, bhh, Wlin, blin, out, lstm, sh)

    if (xf16) { if (mode == 1) LAUNCH_MAIN(1, true);  else LAUNCH_MAIN(2, true); }
    else      { if (mode == 1) LAUNCH_MAIN(1, false); else LAUNCH_MAIN(2, false); }
#undef LAUNCH_MAIN

    if (mode == 1) {
        pass_lstm<<<dim3(BB * 32), dim3(256), 0, stream>>>(sh, lstm);
        pass_out <<<dim3(T4), dim3(512), 0, stream>>>(sh, Wlin, blin, out);
    }
}